// Round 10
// baseline (297.843 us; speedup 1.0000x reference)
//
#include <hip/hip_runtime.h>
#include <hip/hip_fp16.h>
#include <math.h>
#include <stdint.h>

// VQ via f16x3 split MFMA (32x32x16): dot = (hi.hi + hi.lo + lo.hi) * 2^-20.
// diff = (v2 - 2*dot) + c2 fp32-rounded per np; argmin codes 1..4095, ties -> lowest n.
// R10: A-hi via LDS, A-lo via fragment-packed global (feed rebalance LDS<->L2),
// dual-locality XCD swizzle (16 mblk x 16 panel per XCD), compact Bp cells,
// finalize fused into gather via spread atomics + done counter. 3 kernels.

#define M_TOTAL 16384
#define NCODES  4096
#define D_DIM   256

#define OUT_OFF_IDX  (M_TOTAL * D_DIM)
#define OUT_OFF_LOSS (OUT_OFF_IDX + M_TOTAL)

#define VPLANE (M_TOTAL * D_DIM)

typedef _Float16 half8 __attribute__((ext_vector_type(8)));
typedef float    float16v __attribute__((ext_vector_type(16)));

// ---- fused prep ----
// blocks 0..255: W -> Bp (compact fragment cells) + c2; block 0 inits lossP/cnt
// blocks 256..1279: V -> Vhi (row-major) + Aplo (fragment-packed lo) + v2; first 64 init pk
// Bp cell (panel32, kstep): 1024 halves = [hi 512 | lo 512], half idx = lhi*256 + (n&31)*8 + (k&7)
// Aplo: ((((mblk*2+wr)*4+mb)*16+kstep)*64 + lane)*8, lane = lhi*32 + (m&31)
__global__ __launch_bounds__(256) void prep_kernel(
    const float* __restrict__ V, const float* __restrict__ W,
    _Float16* __restrict__ Vhi, _Float16* __restrict__ Aplo,
    _Float16* __restrict__ Bp, float* __restrict__ v2, float* __restrict__ c2,
    uint64_t* __restrict__ pk, float* __restrict__ lossP, int* __restrict__ cnt)
{
  __shared__ float T[16 * 264];
  const int t = threadIdx.x;
  const int rloc = t >> 4, seg = t & 15;
  const bool isW = blockIdx.x < 256;
  const int bid2 = isW ? blockIdx.x : (blockIdx.x - 256);
  const int row = bid2 * 16 + rloc;
  const float* X = isW ? W : V;

  if (!isW && bid2 < 64) pk[bid2 * 256 + t] = ~0ULL;          // init argmin array
  if (isW && bid2 == 0) { if (t < 64) lossP[t] = 0.0f; if (t == 64) *cnt = 0; }

  const float* src = X + (size_t)row * D_DIM + seg * 16;
  float4 x[4];
#pragma unroll
  for (int u = 0; u < 4; ++u) x[u] = ((const float4*)src)[u];
  union { half8 v; _Float16 e[8]; } uh[2], ul[2];
#pragma unroll
  for (int u = 0; u < 4; ++u) {
    float e4[4] = {x[u].x, x[u].y, x[u].z, x[u].w};
#pragma unroll
    for (int j = 0; j < 4; ++j) {
      const int e = u * 4 + j;
      float s = e4[j] * 1024.0f;            // exact pow2 scale
      _Float16 h = (_Float16)s;             // RN
      uh[e >> 3].e[e & 7] = h;
      ul[e >> 3].e[e & 7] = (_Float16)(s - (float)h);  // RN of exact residual
    }
    *(float4*)&T[rloc * 264 + seg * 16 + u * 4] = x[u];
  }
  if (isW) {
    const int panel = row >> 5, nin = row & 31;
    _Float16* dst = Bp + ((size_t)panel * 16 + seg) * 1024 + nin * 8;
#pragma unroll
    for (int lh = 0; lh < 2; ++lh) {
      *(half8*)(dst + lh * 256)       = uh[lh].v;   // hi
      *(half8*)(dst + 512 + lh * 256) = ul[lh].v;   // lo
    }
  } else {
    _Float16* hd = Vhi + (size_t)row * D_DIM + seg * 16;
    *(half8*)hd = uh[0].v; *(half8*)(hd + 8) = uh[1].v;
    const int mblk = row >> 8, wrr = (row >> 7) & 1, mbb = (row >> 5) & 3, nl = row & 31;
    _Float16* ad = Aplo + ((((size_t)mblk * 2 + wrr) * 4 + mbb) * 16 + seg) * 512 + nl * 8;
    *(half8*)ad        = ul[0].v;             // lhi=0
    *(half8*)(ad + 256) = ul[1].v;            // lhi=1
  }
  __syncthreads();
  // rowsq, numpy pairwise chain order (fadd commutative -> shuffle tree exact)
  const int half = (t >> 3) & 1, j = t & 7;
  const float* tr = &T[rloc * 264 + half * 128 + j];
  float r = __fmul_rn(tr[0], tr[0]);
#pragma unroll
  for (int i = 1; i < 16; ++i) { float e = tr[8 * i]; r = __fadd_rn(r, __fmul_rn(e, e)); }
  r = __fadd_rn(r, __shfl_xor(r, 1));
  r = __fadd_rn(r, __shfl_xor(r, 2));
  r = __fadd_rn(r, __shfl_xor(r, 4));
  r = __fadd_rn(r, __shfl_xor(r, 8));   // pw(0:128) + pw(128:256)
  if ((t & 15) == 0) { if (isW) c2[row] = r; else v2[row] = r; }
}

// ---- main: block 256m x 128n, 4 waves 2x2, wave tile 128m x 64n (Tm=4, Tn=2) ----
// A-hi: LDS dbuf (16 KB/tile). A-lo: direct fragment-packed global, ping-pong.
__global__ __launch_bounds__(256, 2) void vq_mfma_kernel(
    const _Float16* __restrict__ Vhi, const _Float16* __restrict__ Aplo,
    const _Float16* __restrict__ Bp,
    const float* __restrict__ v2, const float* __restrict__ c2,
    uint64_t* __restrict__ pk)
{
  // [0,32768): A-hi dbuf [buf2][8192 halves]; epilogue wbuf 4x1056 u64 = 33792 B
  // [33792, 37888): red2[512]
  __shared__ __align__(16) char smem_raw[37888];
  _Float16* As = (_Float16*)smem_raw;
  uint64_t* red2 = (uint64_t*)(smem_raw + 33792);

  const int tid  = threadIdx.x;
  const int lane = tid & 63;
  const int wave = tid >> 6;
  const int wr = wave >> 1, wc = wave & 1;
  const int l31 = lane & 31, lhi = lane >> 5;

  const int bid = blockIdx.x;
  // dual-locality swizzle: XCD x gets 16 mblks x 16 panels (A-lo 2MB + B 2MB, L2-resident)
  const int xcd = bid & 7, jj = bid >> 3;
  const int mblk  = (xcd >> 1) * 16 + (jj & 15);
  const int panel = (xcd & 1) * 16 + (jj >> 4);
  const int m0 = mblk * 256;
  const int n0 = panel * 128;
  const int p32 = panel * 4 + wc * 2;

  // A-hi staging map: g = tid + 256u -> m = g>>2, kb = g&3, chunk c = kb^(m&3)
  int src[4], dst[4];
#pragma unroll
  for (int u = 0; u < 4; ++u) {
    const int g = tid + 256 * u, m = g >> 2, kb = g & 3;
    src[u] = (m0 + m) * D_DIM + kb * 8;
    dst[u] = m * 32 + (kb ^ (m & 3)) * 8;
  }

  float16v acc[4][2];
#pragma unroll
  for (int mb = 0; mb < 4; ++mb)
#pragma unroll
    for (int nb = 0; nb < 2; ++nb) acc[mb][nb] = (float16v)0.0f;

  half8 sh[4];
#pragma unroll
  for (int u = 0; u < 4; ++u) sh[u] = *(const half8*)(Vhi + src[u]);
#pragma unroll
  for (int u = 0; u < 4; ++u) *(half8*)(As + dst[u]) = sh[u];

  const _Float16* abase = Aplo + (((size_t)mblk * 2 + wr) * 4) * 16 * 512 + lane * 8;
  half8 alp[2][4];                      // A-lo ping-pong by kstep parity
#pragma unroll
  for (int mb = 0; mb < 4; ++mb)
    alp[0][mb] = *(const half8*)(abase + (mb * 16 + 0) * 512);

  half8 bh[2][2], bl[2][2];             // B ping-pong by kstep parity
#pragma unroll
  for (int nb = 0; nb < 2; ++nb) {
    const _Float16* bp = Bp + ((size_t)(p32 + nb) * 16) * 1024 + lane * 8;
    bh[0][nb] = *(const half8*)bp;
    bl[0][nb] = *(const half8*)(bp + 512);
  }
  __syncthreads();                      // buf0 visible

  for (int kt = 0; kt < 8; ++kt) {
    const int cur = kt & 1;
    const _Float16* Ac = As + cur * 8192;
    if (kt < 7) {                       // global -> regs for next A-hi tile
#pragma unroll
      for (int u = 0; u < 4; ++u) sh[u] = *(const half8*)(Vhi + src[u] + (kt + 1) * 32);
    }
#pragma unroll
    for (int ks = 0; ks < 2; ++ks) {
      const int kstep = kt * 2 + ks;
      const int pcur = kstep & 1, pnxt = pcur ^ 1;
      if (kstep < 15) {                 // B + A-lo prefetch overlap MFMAs
#pragma unroll
        for (int nb = 0; nb < 2; ++nb) {
          const _Float16* bp = Bp + ((size_t)(p32 + nb) * 16 + kstep + 1) * 1024 + lane * 8;
          bh[pnxt][nb] = *(const half8*)bp;
          bl[pnxt][nb] = *(const half8*)(bp + 512);
        }
#pragma unroll
        for (int mb = 0; mb < 4; ++mb)
          alp[pnxt][mb] = *(const half8*)(abase + (mb * 16 + kstep + 1) * 512);
      }
      half8 ah[4];
#pragma unroll
      for (int mb = 0; mb < 4; ++mb) {
        const int m = wr * 128 + mb * 32 + l31;
        const int c = (ks * 2 + lhi) ^ (m & 3);
        ah[mb] = *(const half8*)(Ac + m * 32 + c * 8);
      }
      // product-major: 8 independent accs per product
#pragma unroll
      for (int nb = 0; nb < 2; ++nb)
#pragma unroll
        for (int mb = 0; mb < 4; ++mb)
          acc[mb][nb] = __builtin_amdgcn_mfma_f32_32x32x16_f16(ah[mb], bh[pcur][nb], acc[mb][nb], 0, 0, 0);
#pragma unroll
      for (int nb = 0; nb < 2; ++nb)
#pragma unroll
        for (int mb = 0; mb < 4; ++mb)
          acc[mb][nb] = __builtin_amdgcn_mfma_f32_32x32x16_f16(ah[mb], bl[pcur][nb], acc[mb][nb], 0, 0, 0);
#pragma unroll
      for (int nb = 0; nb < 2; ++nb)
#pragma unroll
        for (int mb = 0; mb < 4; ++mb)
          acc[mb][nb] = __builtin_amdgcn_mfma_f32_32x32x16_f16(alp[pcur][mb], bh[pcur][nb], acc[mb][nb], 0, 0, 0);
    }
    if (kt < 7) {                       // write next A-hi tile into other buffer
      _Float16* An = As + (cur ^ 1) * 8192;
#pragma unroll
      for (int u = 0; u < 4; ++u) *(half8*)(An + dst[u]) = sh[u];
    }
    __syncthreads();                    // one barrier per kt
  }

  // ---- epilogue: diff = (v2 - 2*dot) + c2 (np order), argmin, tie -> lowest n ----
  float c2r[2];
#pragma unroll
  for (int nb = 0; nb < 2; ++nb) c2r[nb] = c2[n0 + wc * 64 + nb * 32 + l31];

  uint64_t* wbuf = (uint64_t*)smem_raw + wave * 1056;   // 32 rows x 33 u64, per wave

#pragma unroll
  for (int mb = 0; mb < 4; ++mb) {
#pragma unroll
    for (int r = 0; r < 16; ++r) {
      const int rowin = (r & 3) + 8 * (r >> 2) + 4 * lhi;
      const float v2m = v2[m0 + wr * 128 + mb * 32 + rowin];
      uint64_t b = ~0ULL;
#pragma unroll
      for (int nb = 0; nb < 2; ++nb) {
        const int n = n0 + wc * 64 + nb * 32 + l31;
        float dot = acc[mb][nb][r] * 0x1p-20f;            // exact pow2 unscale
        float dd  = __fadd_rn(__fsub_rn(v2m, 2.0f * dot), c2r[nb]);
        if (n == 0) dd = INFINITY;                        // exclude code 0
        uint64_t p = ((uint64_t)__float_as_uint(dd) << 32) | (uint32_t)n;
        if (p < b) b = p;                                 // dd>0 -> bits monotonic
      }
      wbuf[(r * 2 + lhi) * 33 + l31] = b;
    }
    __syncthreads();
    {
      const int f = lane >> 1, hf = lane & 1;
      const uint64_t* rp = wbuf + f * 33 + hf * 16;
      uint64_t m = rp[0];
#pragma unroll
      for (int i = 1; i < 16; ++i) { uint64_t v = rp[i]; if (v < m) m = v; }
      uint64_t o = __shfl_xor((unsigned long long)m, 1);
      if (o < m) m = o;
      if (hf == 0) {
        const int r_ = f >> 1, lh2 = f & 1;
        const int rowin = (r_ & 3) + 8 * (r_ >> 2) + 4 * lh2;
        red2[(wr * 128 + mb * 32 + rowin) * 2 + wc] = m;
      }
    }
    __syncthreads();
  }

  uint64_t a0 = red2[tid * 2], a1 = red2[tid * 2 + 1];
  atomicMin((unsigned long long*)&pk[m0 + tid], (unsigned long long)(a0 < a1 ? a0 : a1));
}

// ---- gather + fused loss finalize: one wave per query; last block writes loss/used ----
__global__ __launch_bounds__(256) void gather_kernel(
    const float* __restrict__ V, const float* __restrict__ W,
    const uint64_t* __restrict__ pk,
    float* __restrict__ out, float* __restrict__ outIdx,
    float* __restrict__ lossP, int* __restrict__ cnt, float* __restrict__ lossOut)
{
  __shared__ float sred[4];
  __shared__ int lastFlag;
  const int wv = threadIdx.x >> 6;
  const int q = blockIdx.x * 4 + wv;
  const int l = threadIdx.x & 63;
  const uint64_t b = pk[q];             // wave-uniform broadcast load
  float4 vv = *(const float4*)(V + (size_t)q * D_DIM + l * 4);
  const float inv = 0.00390625f;
  bool ne = (vv.x != inv) | (vv.y != inv) | (vv.z != inv) | (vv.w != inv);
  const int idx = __ballot(ne) ? (int)(uint32_t)b : 0;
  float4 o4 = *(const float4*)(W + (size_t)idx * D_DIM + l * 4);
  *(float4*)(out + (size_t)q * D_DIM + l * 4) = o4;
  if (l == 0) outIdx[q] = (float)idx;
  float dx = o4.x - vv.x, dy = o4.y - vv.y, dz = o4.z - vv.z, dw = o4.w - vv.w;
  float s = dx * dx + dy * dy + dz * dz + dw * dw;
#pragma unroll
  for (int off = 32; off; off >>= 1) s += __shfl_xor(s, off);
  if (l == 0) sred[wv] = s;
  __syncthreads();
  if (threadIdx.x == 0) {
    float total = sred[0] + sred[1] + sred[2] + sred[3];
    atomicAdd(&lossP[blockIdx.x & 63], total);
    __threadfence();
    int old = atomicAdd(cnt, 1);
    lastFlag = (old == gridDim.x - 1);
  }
  __syncthreads();
  if (lastFlag && wv == 0) {            // last block: reduce the 64 spread partials
    float p = atomicAdd(&lossP[l], 0.0f);   // coherent device-scope read
#pragma unroll
    for (int off = 32; off; off >>= 1) p += __shfl_xor(p, off);
    if (l == 0) {
      lossOut[0] = (float)((double)p / (double)(M_TOTAL * D_DIM));  // loss
      lossOut[1] = 0.0f;                                            // used
    }
  }
}

extern "C" void kernel_launch(void* const* d_in, const int* in_sizes, int n_in,
                              void* d_out, int out_size, void* d_ws, size_t ws_size,
                              hipStream_t stream) {
  const float* V = (const float*)d_in[0];   // 16384 x 256
  const float* W = (const float*)d_in[1];   // 4096 x 256
  float* out = (float*)d_out;

  // Vhi (8 MB) + Aplo (8 MB) live in d_out's out-region; gather overwrites later.
  _Float16* Vhi  = (_Float16*)d_out;
  _Float16* Aplo = Vhi + VPLANE;

  char* ws = (char*)d_ws;
  _Float16* Bp  = (_Float16*)(ws);                        // compact packed W frags: 4 MB
  float*    c2  = (float*)(ws + 4194304);                 // 16 KB
  float*    v2  = (float*)(ws + 4194304 + 16384);         // 64 KB
  uint64_t* pk  = (uint64_t*)(ws + 4194304 + 16384 + 65536);   // 16384 u64 = 128 KB
  float*    lossP = (float*)(ws + 4194304 + 16384 + 65536 + 131072);  // 64 f
  int*      cnt   = (int*)(ws + 4194304 + 16384 + 65536 + 131072 + 256);

  prep_kernel<<<1280, 256, 0, stream>>>(V, W, Vhi, Aplo, Bp, v2, c2, pk, lossP, cnt);
  vq_mfma_kernel<<<2048, 256, 0, stream>>>(Vhi, Aplo, Bp, v2, c2, pk);
  gather_kernel<<<M_TOTAL / 4, 256, 0, stream>>>(V, W, pk, out, out + OUT_OFF_IDX, lossP, cnt,
                                                 out + OUT_OFF_LOSS);
}